// Round 2
// baseline (774.587 us; speedup 1.0000x reference)
//
#include <hip/hip_runtime.h>
#include <hip/hip_bf16.h>

// GCN 2-layer, single mega-kernel with MANUAL grid barriers (plain launch, no
// cooperative API -> graph-capture-safe, no occupancy-query dependence).
// Phases: P1 bucketize | P2 build padded-CSR + dinv | P3 MFMA linear1 -> h1s
// (bf16, pre-scaled by dinv) | P4 agg + fused linear2 -> h2s | P5 agg + bias +
// log_softmax -> out.  Grid = 3 blocks/CU (guaranteed co-resident: LDS 26.6KB*3
// = 80/160KB, 12 waves/CU <= 16-wave cap at 128 VGPR via launch_bounds(256,4)).
// flags[0]=1 if floats bf16 else fp32; flags[1]=1 if edge_index int64 else int32.

constexpr int D_IN  = 128;
constexpr int D_HID = 64;
constexpr int D_OUT = 16;

constexpr int WSHIFT  = 9;       // bucket = dst >> 9 (512 nodes/bucket)
constexpr int MAXB    = 256;     // max buckets (n <= 131072)
constexpr int BCAP    = 12288;   // gbuf bucket capacity (mean ~8163 at E/N=16)
constexpr int CSRCAP  = 16384;   // csr bucket region (BCAP + 512*8 padding)
constexpr int BIN_CAP = 24;      // LDS bin cap (mean ~10.4/chunk-bucket at CHUNK=2048)
constexpr int CHUNK   = 2048;

typedef __attribute__((ext_vector_type(8))) short bf16x8;
typedef __attribute__((ext_vector_type(4))) float f32x4;

__device__ inline float bflo(unsigned u){ return __uint_as_float(u << 16); }
__device__ inline float bfhi(unsigned u){ return __uint_as_float(u & 0xffff0000u); }
__device__ inline unsigned f2bu(float f){
    __hip_bfloat16 h = __float2bfloat16(f);
    return (unsigned)*reinterpret_cast<unsigned short*>(&h);
}
__device__ inline float sigf(float x){ return 1.0f / (1.0f + __expf(-x)); }

// Manual grid barrier. Requires all gridDim.x blocks co-resident (guaranteed by
// grid sizing). Release: __syncthreads drains this block's stores to L2, then
// thread-0 __threadfence emits buffer_wbl2 sc1 (agent release, cross-XCD
// visible) before the device-scope arrive. Acquire: spin, then __threadfence
// (buffer_inv sc1) so this XCD's L2 drops stale lines.
__device__ inline void gbar(unsigned* ctr){
    __syncthreads();
    if (threadIdx.x == 0){
        __threadfence();
        __hip_atomic_fetch_add(ctr, 1u, __ATOMIC_RELEASE, __HIP_MEMORY_SCOPE_AGENT);
        while (__hip_atomic_load(ctr, __ATOMIC_RELAXED, __HIP_MEMORY_SCOPE_AGENT) < gridDim.x)
            __builtin_amdgcn_s_sleep(16);
        __threadfence();
    }
    __syncthreads();
}

__global__ __launch_bounds__(256, 4) void k_mega(
    const unsigned* __restrict__ xraw, const int* __restrict__ ei,
    const unsigned* __restrict__ w1raw, const unsigned* __restrict__ b1raw,
    const unsigned* __restrict__ w2raw, const unsigned* __restrict__ b2raw,
    int* __restrict__ flags, unsigned* __restrict__ bar,
    unsigned* __restrict__ gcur, unsigned* __restrict__ gbuf,
    unsigned* __restrict__ off, unsigned* __restrict__ offend,
    float* __restrict__ dinv, int* __restrict__ csr,
    unsigned short* __restrict__ h1s, unsigned short* __restrict__ h2s,
    void* __restrict__ out, int n, int ne, int B, int nchunk)
{
    __shared__ unsigned smem[512 + MAXB * BIN_CAP];   // 6656 words = 26.6 KB (phase union)
    __shared__ int s_i64;

    const int t = threadIdx.x, lane = t & 63, wv = t >> 6;
    const int G = (int)gridDim.x;

    // ================= P1: bucketize edges by dst>>9 + dtype detect =================
    if (wv == 0){
        int w = ei[2 * lane + 1];
        unsigned long long m = __ballot(w == 0);
        if (lane == 0) s_i64 = (__popcll(m) > 48) ? 1 : 0;
        if (blockIdx.x == 0){
            unsigned u = xraw[lane];
            unsigned h0 = u & 0xffffu, h1 = u >> 16;
            unsigned ex0 = (h0 >> 7) & 0xffu, ex1 = (h1 >> 7) & 0xffu;
            bool bad0 = !((h0 & 0x7fffu) == 0 || (ex0 >= 97 && ex0 <= 157));
            bool bad1 = !((h1 & 0x7fffu) == 0 || (ex1 >= 97 && ex1 <= 157));
            unsigned long long m0 = __ballot(bad0);
            unsigned long long m1 = __ballot(bad1);
            if (lane == 0){
                int bad = __popcll(m0) + __popcll(m1);
                flags[0] = (bad > 8) ? 0 : 1;
                flags[1] = s_i64;
            }
        }
    }
    __syncthreads();
    const int i64 = s_i64;
    const bool vec = ((ne & 1) == 0);

    {
        unsigned* bcnt  = smem;          // [256]
        unsigned* bbase = smem + 256;    // [256]
        unsigned* bins  = smem + 512;    // [256 * BIN_CAP]

        for (int ch = (int)blockIdx.x; ch < nchunk; ch += G){
            if (t < MAXB) bcnt[t] = 0u;
            __syncthreads();
            const int e0 = ch * CHUNK;
            #pragma unroll
            for (int k = 0; k < CHUNK / 512; ++k){
                int e = e0 + k * 512 + 2 * t;
                int s0, d0, s1, d1;
                int cntE = 0;
                if (vec && e < ne){
                    if (i64){
                        int4 sp = *(const int4*)&ei[2 * e];
                        int4 dp = *(const int4*)&ei[2 * (ne + e)];
                        s0 = sp.x; s1 = sp.z; d0 = dp.x; d1 = dp.z;
                    } else {
                        int2 sp = *(const int2*)&ei[e];
                        int2 dp = *(const int2*)&ei[ne + e];
                        s0 = sp.x; s1 = sp.y; d0 = dp.x; d1 = dp.y;
                    }
                    cntE = 2;
                } else {
                    if (e < ne){
                        if (i64){ s0 = ei[2*e]; d0 = ei[2*(ne+e)]; }
                        else    { s0 = ei[e];   d0 = ei[ne+e]; }
                        cntE = 1;
                        if (e + 1 < ne){
                            if (i64){ s1 = ei[2*(e+1)]; d1 = ei[2*(ne+e+1)]; }
                            else    { s1 = ei[e+1];     d1 = ei[ne+e+1]; }
                            cntE = 2;
                        }
                    }
                }
                #pragma unroll
                for (int j = 0; j < 2; ++j){
                    if (j < cntE){
                        int s = j ? s1 : s0, d = j ? d1 : d0;
                        int b = d >> WSHIFT;
                        unsigned v = ((unsigned)s << WSHIFT) | ((unsigned)d & ((1u << WSHIFT) - 1));
                        unsigned p = atomicAdd(&bcnt[b], 1u);
                        if (p < (unsigned)BIN_CAP){
                            bins[b * BIN_CAP + p] = v;
                        } else {
                            unsigned g2 = atomicAdd(&gcur[b], 1u);
                            gbuf[(size_t)b * BCAP + g2] = v;
                        }
                    }
                }
            }
            __syncthreads();
            if (t < B){
                unsigned c = min(bcnt[t], (unsigned)BIN_CAP);
                bbase[t] = atomicAdd(&gcur[t], c);
            }
            __syncthreads();
            for (int b = wv; b < B; b += 4){
                unsigned c = min(bcnt[b], (unsigned)BIN_CAP);
                unsigned ba = bbase[b];
                for (unsigned o = (unsigned)lane; o < c; o += 64)
                    gbuf[(size_t)b * BCAP + ba + o] = bins[b * BIN_CAP + o];
            }
            __syncthreads();
        }
    }

    gbar(&bar[0]);

    // ================= P2: per-bucket hist + scan + padded CSR (256 thr/bucket) =================
    {
        unsigned* hist  = smem;          // [512]
        unsigned* wsums = smem + 512;    // [4]
        for (int b = (int)blockIdx.x; b < B; b += G){
            const int base = b << WSHIFT;
            const int nodes = min(512, n - base);
            const unsigned bb = (unsigned)b * CSRCAP;
            hist[t] = 0u; hist[t + 256] = 0u;
            __syncthreads();
            const unsigned cnt = gcur[b];
            const unsigned* mybuf = gbuf + (size_t)b * BCAP;
            for (unsigned i = t; i < cnt; i += 256)
                atomicAdd(&hist[mybuf[i] & ((1u << WSHIFT) - 1)], 1u);
            __syncthreads();
            // thread t owns local nodes 2t, 2t+1
            unsigned v0 = hist[2*t], v1 = hist[2*t+1];
            unsigned p0 = (v0 + 7u) & ~7u, p1 = (v1 + 7u) & ~7u;
            unsigned x = p0 + p1, xi = x;
            #pragma unroll
            for (int o = 1; o < 64; o <<= 1){
                unsigned y = __shfl_up(xi, o, 64);
                if (lane >= o) xi += y;
            }
            if (lane == 63) wsums[wv] = xi;
            __syncthreads();
            if (t == 0){
                unsigned run = 0;
                #pragma unroll
                for (int w8 = 0; w8 < 4; ++w8){ unsigned tv = wsums[w8]; wsums[w8] = run; run += tv; }
            }
            __syncthreads();
            const unsigned ex = xi - x + wsums[wv];    // exclusive prefix, node 2t
            if (2*t < nodes){
                off[base + 2*t]    = bb + ex;
                offend[base + 2*t] = bb + ex + p0;
                dinv[base + 2*t]   = rsqrtf(1.0f + (float)v0);
            }
            if (2*t+1 < nodes){
                off[base + 2*t+1]    = bb + ex + p0;
                offend[base + 2*t+1] = bb + ex + p0 + p1;
                dinv[base + 2*t+1]   = rsqrtf(1.0f + (float)v1);
            }
            __syncthreads();
            // reuse hist as fill cursors (each thread touches only its own 2 slots)
            hist[2*t] = ex; hist[2*t+1] = ex + p0;
            __syncthreads();
            for (unsigned i = t; i < cnt; i += 256){
                unsigned rec = mybuf[i];
                unsigned pos = atomicAdd(&hist[rec & ((1u << WSHIFT) - 1)], 1u);
                csr[bb + pos] = (int)(rec >> WSHIFT);
            }
            __syncthreads();
            // padding rows -> node n (zero row)
            if (2*t < nodes){
                for (unsigned j2 = ex + v0; j2 < ex + p0; ++j2) csr[bb + j2] = n;
            }
            if (2*t+1 < nodes){
                unsigned o1 = ex + p0;
                for (unsigned j2 = o1 + v1; j2 < o1 + p1; ++j2) csr[bb + j2] = n;
            }
            __syncthreads();
        }
    }

    gbar(&bar[1]);

    // ================= P3: linear1 (MFMA): h1s = (x @ W1) * dinv; row n = 0 =================
    const int isBf16 = flags[0];
    if (blockIdx.x == 0 && t < 16)
        ((uint2*)(h1s + (size_t)n * D_HID))[t] = make_uint2(0u, 0u);
    {
        const int m = lane & 15, q = lane >> 4;
        const int ntiles = (n + 15) >> 4;
        for (int tile = (int)blockIdx.x * 4 + wv; tile < ntiles; tile += G * 4){
            const int node0 = tile << 4;
            int arow = node0 + m; if (arow >= n) arow = n - 1;
            f32x4 ac0 = {0,0,0,0}, ac1 = {0,0,0,0}, ac2 = {0,0,0,0}, ac3 = {0,0,0,0};
            #pragma unroll
            for (int kc = 0; kc < 4; ++kc){
                bf16x8 a;
                if (isBf16){
                    uint4 u = *(const uint4*)((const unsigned short*)xraw + (size_t)arow * D_IN + kc*32 + q*8);
                    a = *reinterpret_cast<bf16x8*>(&u);
                } else {
                    const float* xp = (const float*)xraw + (size_t)arow * D_IN + kc*32 + q*8;
                    float4 f0 = *(const float4*)xp;
                    float4 f1 = *(const float4*)(xp + 4);
                    a[0]=(short)f2bu(f0.x); a[1]=(short)f2bu(f0.y); a[2]=(short)f2bu(f0.z); a[3]=(short)f2bu(f0.w);
                    a[4]=(short)f2bu(f1.x); a[5]=(short)f2bu(f1.y); a[6]=(short)f2bu(f1.z); a[7]=(short)f2bu(f1.w);
                }
                // per-kc weight fragments (L1-resident; keeps VGPR < 128)
                bf16x8 b0, b1, b2, b3;
                if (isBf16){
                    const unsigned short* w = (const unsigned short*)w1raw;
                    #pragma unroll
                    for (int j = 0; j < 8; ++j){
                        int r = (kc*32 + q*8 + j) * D_HID + m;
                        b0[j] = (short)w[r];      b1[j] = (short)w[r + 16];
                        b2[j] = (short)w[r + 32]; b3[j] = (short)w[r + 48];
                    }
                } else {
                    const float* w = (const float*)w1raw;
                    #pragma unroll
                    for (int j = 0; j < 8; ++j){
                        int r = (kc*32 + q*8 + j) * D_HID + m;
                        b0[j] = (short)f2bu(w[r]);      b1[j] = (short)f2bu(w[r + 16]);
                        b2[j] = (short)f2bu(w[r + 32]); b3[j] = (short)f2bu(w[r + 48]);
                    }
                }
                ac0 = __builtin_amdgcn_mfma_f32_16x16x32_bf16(a, b0, ac0, 0, 0, 0);
                ac1 = __builtin_amdgcn_mfma_f32_16x16x32_bf16(a, b1, ac1, 0, 0, 0);
                ac2 = __builtin_amdgcn_mfma_f32_16x16x32_bf16(a, b2, ac2, 0, 0, 0);
                ac3 = __builtin_amdgcn_mfma_f32_16x16x32_bf16(a, b3, ac3, 0, 0, 0);
            }
            #pragma unroll
            for (int i = 0; i < 4; ++i){
                int nr = node0 + q*4 + i;
                if (nr < n){
                    float di = dinv[nr];
                    unsigned short* o = h1s + (size_t)nr * D_HID + m;
                    o[0]  = (unsigned short)f2bu(ac0[i] * di);
                    o[16] = (unsigned short)f2bu(ac1[i] * di);
                    o[32] = (unsigned short)f2bu(ac2[i] * di);
                    o[48] = (unsigned short)f2bu(ac3[i] * di);
                }
            }
        }
    }

    gbar(&bar[2]);

    // ================= P4: aggA + fused linear2 -> h2s =================
    {
        unsigned short* act_s = (unsigned short*)smem;    // [16][72] padded
        const int grp = lane >> 4;            // dst within wave (0..3)
        const int f   = lane & 15;            // uint2 index within 64-feature row
        const int dl  = wv * 4 + grp;         // dst within block (0..15)
        const int m0 = lane & 15, q0 = lane >> 4;

        bf16x8 w2f[2];
        if (wv == 0){
            if (isBf16){
                const unsigned short* w = (const unsigned short*)w2raw;
                #pragma unroll
                for (int kc = 0; kc < 2; ++kc)
                    #pragma unroll
                    for (int j = 0; j < 8; ++j)
                        w2f[kc][j] = (short)w[(kc*32 + q0*8 + j) * D_OUT + m0];
            } else {
                const float* w = (const float*)w2raw;
                #pragma unroll
                for (int kc = 0; kc < 2; ++kc)
                    #pragma unroll
                    for (int j = 0; j < 8; ++j)
                        w2f[kc][j] = (short)f2bu(w[(kc*32 + q0*8 + j) * D_OUT + m0]);
            }
            if (blockIdx.x == 0 && lane < 4)
                ((uint2*)(h2s + (size_t)n * D_OUT))[lane] = make_uint2(0u, 0u);
        }

        const int ng = (n + 15) >> 4;
        for (int g = (int)blockIdx.x; g < ng; g += G){
            const int d = g * 16 + dl;
            if (d < n){
                const int beg = (int)off[d], end = (int)offend[d];
                float a0=0.f, a1=0.f, a2=0.f, a3=0.f;
                for (int i = beg; i < end; i += 8){
                    uint4 cA = *(const uint4*)&csr[i];
                    uint4 cB = *(const uint4*)&csr[i + 4];
                    uint2 u0 = *(const uint2*)&h1s[(size_t)(unsigned)cA.x * D_HID + f * 4];
                    uint2 u1 = *(const uint2*)&h1s[(size_t)(unsigned)cA.y * D_HID + f * 4];
                    uint2 u2 = *(const uint2*)&h1s[(size_t)(unsigned)cA.z * D_HID + f * 4];
                    uint2 u3 = *(const uint2*)&h1s[(size_t)(unsigned)cA.w * D_HID + f * 4];
                    uint2 u4 = *(const uint2*)&h1s[(size_t)(unsigned)cB.x * D_HID + f * 4];
                    uint2 u5 = *(const uint2*)&h1s[(size_t)(unsigned)cB.y * D_HID + f * 4];
                    uint2 u6 = *(const uint2*)&h1s[(size_t)(unsigned)cB.z * D_HID + f * 4];
                    uint2 u7 = *(const uint2*)&h1s[(size_t)(unsigned)cB.w * D_HID + f * 4];
                    a0 += bflo(u0.x) + bflo(u1.x) + bflo(u2.x) + bflo(u3.x)
                        + bflo(u4.x) + bflo(u5.x) + bflo(u6.x) + bflo(u7.x);
                    a1 += bfhi(u0.x) + bfhi(u1.x) + bfhi(u2.x) + bfhi(u3.x)
                        + bfhi(u4.x) + bfhi(u5.x) + bfhi(u6.x) + bfhi(u7.x);
                    a2 += bflo(u0.y) + bflo(u1.y) + bflo(u2.y) + bflo(u3.y)
                        + bflo(u4.y) + bflo(u5.y) + bflo(u6.y) + bflo(u7.y);
                    a3 += bfhi(u0.y) + bfhi(u1.y) + bfhi(u2.y) + bfhi(u3.y)
                        + bfhi(u4.y) + bfhi(u5.y) + bfhi(u6.y) + bfhi(u7.y);
                }
                uint2 su = *(const uint2*)&h1s[(size_t)d * D_HID + f * 4];
                a0 += bflo(su.x); a1 += bfhi(su.x);
                a2 += bflo(su.y); a3 += bfhi(su.y);
                const float dd = dinv[d];
                float b0, b1v, b2v, b3v;
                if (isBf16){
                    uint2 bu = ((const uint2*)b1raw)[f];
                    b0 = bflo(bu.x); b1v = bfhi(bu.x); b2v = bflo(bu.y); b3v = bfhi(bu.y);
                } else {
                    float4 bb4 = ((const float4*)b1raw)[f];
                    b0 = bb4.x; b1v = bb4.y; b2v = bb4.z; b3v = bb4.w;
                }
                act_s[dl*72 + f*4 + 0] = (unsigned short)f2bu(sigf(fmaf(a0, dd, b0)));
                act_s[dl*72 + f*4 + 1] = (unsigned short)f2bu(sigf(fmaf(a1, dd, b1v)));
                act_s[dl*72 + f*4 + 2] = (unsigned short)f2bu(sigf(fmaf(a2, dd, b2v)));
                act_s[dl*72 + f*4 + 3] = (unsigned short)f2bu(sigf(fmaf(a3, dd, b3v)));
            } else {
                #pragma unroll
                for (int j = 0; j < 4; ++j) act_s[dl*72 + f*4 + j] = 0;
            }
            __syncthreads();

            if (wv == 0){
                f32x4 acc = {0,0,0,0};
                #pragma unroll
                for (int kc = 0; kc < 2; ++kc){
                    bf16x8 a;
                    #pragma unroll
                    for (int j = 0; j < 8; ++j)
                        a[j] = (short)act_s[m0*72 + kc*32 + q0*8 + j];
                    acc = __builtin_amdgcn_mfma_f32_16x16x32_bf16(a, w2f[kc], acc, 0, 0, 0);
                }
                #pragma unroll
                for (int i = 0; i < 4; ++i){
                    int nr = g * 16 + q0*4 + i;
                    if (nr < n)
                        h2s[(size_t)nr * D_OUT + m0] = (unsigned short)f2bu(acc[i] * dinv[nr]);
                }
            }
            __syncthreads();
        }
    }

    gbar(&bar[3]);

    // ================= P5: aggB + bias + log_softmax -> out =================
    {
        const int grp = lane >> 2;            // dst within wave (0..15)
        const int f   = lane & 3;             // uint2 index within 16-feature row
        const int nw = (n + 15) >> 4;
        for (int w = (int)blockIdx.x * 4 + wv; w < nw; w += G * 4){
            const int d = w * 16 + grp;
            if (d >= n) continue;
            const int beg = (int)off[d], end = (int)offend[d];
            float a0=0.f, a1=0.f, a2=0.f, a3=0.f;
            for (int i = beg; i < end; i += 8){
                uint4 cA = *(const uint4*)&csr[i];
                uint4 cB = *(const uint4*)&csr[i + 4];
                uint2 u0 = *(const uint2*)&h2s[(size_t)(unsigned)cA.x * D_OUT + f * 4];
                uint2 u1 = *(const uint2*)&h2s[(size_t)(unsigned)cA.y * D_OUT + f * 4];
                uint2 u2 = *(const uint2*)&h2s[(size_t)(unsigned)cA.z * D_OUT + f * 4];
                uint2 u3 = *(const uint2*)&h2s[(size_t)(unsigned)cA.w * D_OUT + f * 4];
                uint2 u4 = *(const uint2*)&h2s[(size_t)(unsigned)cB.x * D_OUT + f * 4];
                uint2 u5 = *(const uint2*)&h2s[(size_t)(unsigned)cB.y * D_OUT + f * 4];
                uint2 u6 = *(const uint2*)&h2s[(size_t)(unsigned)cB.z * D_OUT + f * 4];
                uint2 u7 = *(const uint2*)&h2s[(size_t)(unsigned)cB.w * D_OUT + f * 4];
                a0 += bflo(u0.x) + bflo(u1.x) + bflo(u2.x) + bflo(u3.x)
                    + bflo(u4.x) + bflo(u5.x) + bflo(u6.x) + bflo(u7.x);
                a1 += bfhi(u0.x) + bfhi(u1.x) + bfhi(u2.x) + bfhi(u3.x)
                    + bfhi(u4.x) + bfhi(u5.x) + bfhi(u6.x) + bfhi(u7.x);
                a2 += bflo(u0.y) + bflo(u1.y) + bflo(u2.y) + bflo(u3.y)
                    + bflo(u4.y) + bflo(u5.y) + bflo(u6.y) + bflo(u7.y);
                a3 += bfhi(u0.y) + bfhi(u1.y) + bfhi(u2.y) + bfhi(u3.y)
                    + bfhi(u4.y) + bfhi(u5.y) + bfhi(u6.y) + bfhi(u7.y);
            }
            uint2 su = *(const uint2*)&h2s[(size_t)d * D_OUT + f * 4];
            a0 += bflo(su.x); a1 += bfhi(su.x);
            a2 += bflo(su.y); a3 += bfhi(su.y);
            const float dd = dinv[d];
            float b0, b1v, b2v, b3v;
            if (isBf16){
                uint2 bu = ((const uint2*)b2raw)[f];
                b0 = bflo(bu.x); b1v = bfhi(bu.x); b2v = bflo(bu.y); b3v = bfhi(bu.y);
            } else {
                float4 bb4 = ((const float4*)b2raw)[f];
                b0 = bb4.x; b1v = bb4.y; b2v = bb4.z; b3v = bb4.w;
            }
            a0 = fmaf(a0, dd, b0); a1 = fmaf(a1, dd, b1v);
            a2 = fmaf(a2, dd, b2v); a3 = fmaf(a3, dd, b3v);
            float m = fmaxf(fmaxf(a0, a1), fmaxf(a2, a3));
            m = fmaxf(m, __shfl_xor(m, 1, 4));
            m = fmaxf(m, __shfl_xor(m, 2, 4));
            float s = __expf(a0 - m) + __expf(a1 - m) + __expf(a2 - m) + __expf(a3 - m);
            s += __shfl_xor(s, 1, 4);
            s += __shfl_xor(s, 2, 4);
            float ls = m + __logf(s);
            if (isBf16){
                uint2 pk;
                pk.x = f2bu(a0 - ls) | (f2bu(a1 - ls) << 16);
                pk.y = f2bu(a2 - ls) | (f2bu(a3 - ls) << 16);
                *(uint2*)((__hip_bfloat16*)out + (size_t)d * D_OUT + f * 4) = pk;
            } else {
                float4 o4 = make_float4(a0 - ls, a1 - ls, a2 - ls, a3 - ls);
                *(float4*)((float*)out + (size_t)d * D_OUT + f * 4) = o4;
            }
        }
    }
}

extern "C" void kernel_launch(void* const* d_in, const int* in_sizes, int n_in,
                              void* d_out, int out_size, void* d_ws, size_t ws_size,
                              hipStream_t stream)
{
    const unsigned* xraw  = (const unsigned*)d_in[0];
    const int*      ei    = (const int*)d_in[1];
    const unsigned* w1raw = (const unsigned*)d_in[2];
    const unsigned* b1raw = (const unsigned*)d_in[3];
    const unsigned* w2raw = (const unsigned*)d_in[4];
    const unsigned* b2raw = (const unsigned*)d_in[5];

    const int n  = in_sizes[0] / D_IN;   // 100000
    const int ne = in_sizes[1] / 2;      // 1600000
    const int B  = (n + ((1 << WSHIFT) - 1)) >> WSHIFT;   // 196 buckets

    // ws layout (4B words):
    // flags[32] | bar[32] | gcur[256] | dinv[nAl] | off[nAl] | offend[nAl]
    //   | csr[MAXB*CSRCAP] | gbuf[MAXB*BCAP] | h1s[(n+16)*64 bf16] | h2s[(n+16)*16 bf16]
    size_t nAl = ((size_t)n + 255) & ~(size_t)255;
    int*            flags  = (int*)d_ws;
    unsigned*       bar    = (unsigned*)d_ws + 32;
    unsigned*       gcur   = (unsigned*)d_ws + 64;
    float*          dinvp  = (float*)(gcur + 256);
    unsigned*       off    = (unsigned*)(dinvp + nAl);
    unsigned*       offend = off + nAl;
    int*            csr    = (int*)(offend + nAl);
    unsigned*       gbuf   = (unsigned*)(csr + (size_t)MAXB * CSRCAP);
    unsigned short* h1s    = (unsigned short*)(gbuf + (size_t)MAXB * BCAP);
    unsigned short* h2s    = h1s + (size_t)(n + 16) * D_HID;

    const int nchunk = (ne + CHUNK - 1) / CHUNK;

    // Grid: 3 blocks/CU — guaranteed co-resident (LDS 26.6KB*3=80/160KB,
    // 12 waves/CU <= 16-wave cap at 128 VGPR). No occupancy query needed.
    static int s_cus = 0;
    if (s_cus == 0){
        int dev = 0, c = 0;
        (void)hipGetDevice(&dev);
        if (hipDeviceGetAttribute(&c, hipDeviceAttributeMultiprocessorCount, dev) != hipSuccess || c <= 0)
            c = 256;
        s_cus = c;
    }
    const int G = s_cus * 3;

    // zero bar[0..31] + gcur[0..255]
    hipMemsetAsync((char*)d_ws + 32 * sizeof(unsigned), 0, (32 + 256) * sizeof(unsigned), stream);

    k_mega<<<G, 256, 0, stream>>>(xraw, ei, w1raw, b1raw, w2raw, b2raw,
                                  flags, bar, gcur, gbuf, off, offend, dinvp,
                                  csr, h1s, h2s, d_out, n, ne, B, nchunk);
}

// Round 3
// 377.246 us; speedup vs baseline: 2.0533x; 2.0533x over previous
//
#include <hip/hip_runtime.h>
#include <hip/hip_bf16.h>

// GCN 2-layer, 4-kernel pipeline (+1 tiny memset). Bucketized padded-CSR build,
// pre-scaled bf16 intermediates (h1s = h1*dinv), MFMA linear1 FUSED into the
// per-bucket build kernel (dinv is bucket-local -> no global round-trip, and
// the x streaming read overlaps build's latency-bound phases), linear2 fused
// into aggA. Separate kernels (NOT grid-fused): R2 measured that single-kernel
// fusion nukes L2 between phases (wbl2/inv at barriers: 308MB writes) and caps
// the latency-bound gather phases at 12 waves/CU. Kernel boundaries keep L2
// warm and let aggA/aggB run at full occupancy.
// flags[0]=1 if floats bf16 else fp32; flags[1]=1 if edge_index int64 else int32.

constexpr int D_IN  = 128;
constexpr int D_HID = 64;
constexpr int D_OUT = 16;

constexpr int WSHIFT  = 9;       // bucket = dst >> 9 (512 nodes/bucket)
constexpr int MAXB    = 256;     // max buckets (n <= 131072)
constexpr int BCAP    = 12288;   // gbuf bucket capacity (mean ~8163 at E/N=16)
constexpr int CSRCAP  = 16384;   // csr bucket region (BCAP + 512*8 padding)
constexpr int BIN_CAP = 24;      // LDS bin cap per bucket per chunk (mean ~10.5)
constexpr int CHUNK   = 2048;    // 782 chunks -> ~3 blocks/CU (was 391 @ 1.5/CU)

typedef __attribute__((ext_vector_type(8))) short bf16x8;
typedef __attribute__((ext_vector_type(4))) float f32x4;

__device__ inline float bflo(unsigned u){ return __uint_as_float(u << 16); }
__device__ inline float bfhi(unsigned u){ return __uint_as_float(u & 0xffff0000u); }
__device__ inline unsigned f2bu(float f){
    __hip_bfloat16 h = __float2bfloat16(f);
    return (unsigned)*reinterpret_cast<unsigned short*>(&h);
}
__device__ inline float sigf(float x){ return 1.0f / (1.0f + __expf(-x)); }

// ---------------- phase 1: bucketize edges by dst>>9 + on-device dtype detect ----------------
__global__ __launch_bounds__(256) void k_bucketize(
    const int* __restrict__ ei, const unsigned* __restrict__ xraw,
    int* __restrict__ flags, unsigned* __restrict__ gcur,
    unsigned* __restrict__ gbuf, int ne, int B)
{
    __shared__ unsigned bcnt[MAXB];
    __shared__ unsigned bbase[MAXB];
    __shared__ unsigned bins[MAXB * BIN_CAP];   // 24.6 KB -> 26.6 KB total
    __shared__ int s_i64;

    const int t = threadIdx.x, lane = t & 63, wv = t >> 6;
    const int e0 = blockIdx.x * CHUNK;

    if (t < MAXB) bcnt[t] = 0u;
    if (wv == 0){
        int w = ei[2 * lane + 1];
        unsigned long long m = __ballot(w == 0);
        if (lane == 0) s_i64 = (__popcll(m) > 48) ? 1 : 0;
        if (blockIdx.x == 0){
            unsigned u = xraw[lane];
            unsigned h0 = u & 0xffffu, h1 = u >> 16;
            unsigned ex0 = (h0 >> 7) & 0xffu, ex1 = (h1 >> 7) & 0xffu;
            bool bad0 = !((h0 & 0x7fffu) == 0 || (ex0 >= 97 && ex0 <= 157));
            bool bad1 = !((h1 & 0x7fffu) == 0 || (ex1 >= 97 && ex1 <= 157));
            unsigned long long m0 = __ballot(bad0);
            unsigned long long m1 = __ballot(bad1);
            if (lane == 0){
                int bad = __popcll(m0) + __popcll(m1);
                flags[0] = (bad > 8) ? 0 : 1;
                flags[1] = s_i64;
            }
        }
    }
    __syncthreads();
    const int i64 = s_i64;
    const bool vec = ((ne & 1) == 0);

    #pragma unroll
    for (int k = 0; k < CHUNK / 512; ++k){
        int e = e0 + k * 512 + 2 * t;
        int s0, d0, s1, d1;
        int cntE = 0;
        if (vec && e < ne){
            if (i64){
                int4 sp = *(const int4*)&ei[2 * e];
                int4 dp = *(const int4*)&ei[2 * (ne + e)];
                s0 = sp.x; s1 = sp.z; d0 = dp.x; d1 = dp.z;
            } else {
                int2 sp = *(const int2*)&ei[e];
                int2 dp = *(const int2*)&ei[ne + e];
                s0 = sp.x; s1 = sp.y; d0 = dp.x; d1 = dp.y;
            }
            cntE = 2;
        } else {
            if (e < ne){
                if (i64){ s0 = ei[2*e]; d0 = ei[2*(ne+e)]; }
                else    { s0 = ei[e];   d0 = ei[ne+e]; }
                cntE = 1;
                if (e + 1 < ne){
                    if (i64){ s1 = ei[2*(e+1)]; d1 = ei[2*(ne+e+1)]; }
                    else    { s1 = ei[e+1];     d1 = ei[ne+e+1]; }
                    cntE = 2;
                }
            }
        }
        #pragma unroll
        for (int j = 0; j < 2; ++j){
            if (j < cntE){
                int s = j ? s1 : s0, d = j ? d1 : d0;
                int b = d >> WSHIFT;
                unsigned v = ((unsigned)s << WSHIFT) | ((unsigned)d & ((1u << WSHIFT) - 1));
                unsigned p = atomicAdd(&bcnt[b], 1u);
                if (p < (unsigned)BIN_CAP){
                    bins[b * BIN_CAP + p] = v;
                } else {
                    unsigned g = atomicAdd(&gcur[b], 1u);
                    gbuf[(size_t)b * BCAP + g] = v;
                }
            }
        }
    }
    __syncthreads();

    if (t < B){
        unsigned c = min(bcnt[t], (unsigned)BIN_CAP);
        bbase[t] = atomicAdd(&gcur[t], c);
    }
    __syncthreads();

    for (int b = wv; b < B; b += 4){
        unsigned c = min(bcnt[b], (unsigned)BIN_CAP);
        unsigned ba = bbase[b];
        for (unsigned o = lane; o < c; o += 64)
            gbuf[(size_t)b * BCAP + ba + o] = bins[b * BIN_CAP + o];
    }
}

// ---------------- phase 2: per-bucket hist + scan + PADDED csr fill + FUSED linear1 ----------------
// After building this bucket's CSR and dinv (in LDS), the same block runs the
// MFMA linear1 for its own 512 nodes: h1s = (x @ W1) * dinv, bf16.
__global__ __launch_bounds__(1024, 4) void k_build_lin1(
    const unsigned* __restrict__ gbuf, const unsigned* __restrict__ gcnt,
    unsigned* __restrict__ off, unsigned* __restrict__ offend,
    float* __restrict__ dinv, int* __restrict__ csr,
    const unsigned* __restrict__ xraw, const unsigned* __restrict__ w1raw,
    const int* __restrict__ flags, unsigned short* __restrict__ h1s,
    int n, int B)
{
    __shared__ unsigned hist[512];
    __shared__ unsigned offl[512];
    __shared__ unsigned wsums[8];
    __shared__ float    s_dinv[512];

    const int t = threadIdx.x, lane = t & 63, wv = t >> 6;
    const int b = blockIdx.x;
    const int base = b << WSHIFT;
    const int nodes = min(512, n - base);
    const unsigned bb = (unsigned)b * CSRCAP;

    if (t < 512) hist[t] = 0u;
    __syncthreads();
    const unsigned cnt = gcnt[b];
    const unsigned* mybuf = gbuf + (size_t)b * BCAP;

    for (unsigned i = t; i < cnt; i += 1024)
        atomicAdd(&hist[mybuf[i] & ((1u << WSHIFT) - 1)], 1u);
    __syncthreads();

    unsigned v = 0, p = 0, x = 0;
    if (t < 512){
        v = hist[t];
        p = (v + 7u) & ~7u;
        x = p;
        #pragma unroll
        for (int o = 1; o < 64; o <<= 1){
            unsigned y = __shfl_up(x, o, 64);
            if (lane >= o) x += y;
        }
        if (lane == 63) wsums[wv] = x;
    }
    __syncthreads();
    if (t == 0){
        unsigned run = 0;
        #pragma unroll
        for (int w = 0; w < 8; ++w){ unsigned tv = wsums[w]; wsums[w] = run; run += tv; }
    }
    __syncthreads();
    if (t < 512) offl[t] = x - p + wsums[wv];
    __syncthreads();

    if (t < nodes){
        float dv = rsqrtf(1.0f + (float)v);
        off[base + t]    = bb + offl[t];
        offend[base + t] = bb + offl[t] + p;
        dinv[base + t]   = dv;
        s_dinv[t]        = dv;
    }
    __syncthreads();

    if (t < 512) hist[t] = offl[t];
    __syncthreads();

    for (unsigned i = t; i < cnt; i += 1024){
        unsigned rec = mybuf[i];
        unsigned pos = atomicAdd(&hist[rec & ((1u << WSHIFT) - 1)], 1u);
        csr[bb + pos] = (int)(rec >> WSHIFT);
    }
    __syncthreads();

    if (t < nodes){
        unsigned s = offl[t] + v, e2 = offl[t] + p;
        for (unsigned j = s; j < e2; ++j) csr[bb + j] = n;
    }
    __syncthreads();

    // ---- fused linear1 for this bucket's nodes ----
    const int isBf16 = flags[0];
    if (b == 0 && t < 16)
        ((uint2*)(h1s + (size_t)n * D_HID))[t] = make_uint2(0u, 0u);

    const int m = lane & 15, q = lane >> 4;
    const int ntb = (nodes + 15) >> 4;        // <= 32 tiles; 16 waves -> <= 2 tiles/wave
    for (int tt = wv; tt < ntb; tt += 16){
        const int node0 = base + (tt << 4);
        int arow = node0 + m; if (arow >= n) arow = n - 1;
        f32x4 ac0 = {0,0,0,0}, ac1 = {0,0,0,0}, ac2 = {0,0,0,0}, ac3 = {0,0,0,0};
        #pragma unroll
        for (int kc = 0; kc < 4; ++kc){
            bf16x8 a;
            if (isBf16){
                uint4 u = *(const uint4*)((const unsigned short*)xraw + (size_t)arow * D_IN + kc*32 + q*8);
                a = *reinterpret_cast<bf16x8*>(&u);
            } else {
                const float* xp = (const float*)xraw + (size_t)arow * D_IN + kc*32 + q*8;
                float4 f0 = *(const float4*)xp;
                float4 f1 = *(const float4*)(xp + 4);
                a[0]=(short)f2bu(f0.x); a[1]=(short)f2bu(f0.y); a[2]=(short)f2bu(f0.z); a[3]=(short)f2bu(f0.w);
                a[4]=(short)f2bu(f1.x); a[5]=(short)f2bu(f1.y); a[6]=(short)f2bu(f1.z); a[7]=(short)f2bu(f1.w);
            }
            // transient per-kc weight fragments (16KB W1 is L1-resident; keeps VGPR low)
            bf16x8 b0, b1, b2, b3;
            if (isBf16){
                const unsigned short* w = (const unsigned short*)w1raw;
                #pragma unroll
                for (int j = 0; j < 8; ++j){
                    int r = (kc*32 + q*8 + j) * D_HID + m;
                    b0[j] = (short)w[r];      b1[j] = (short)w[r + 16];
                    b2[j] = (short)w[r + 32]; b3[j] = (short)w[r + 48];
                }
            } else {
                const float* w = (const float*)w1raw;
                #pragma unroll
                for (int j = 0; j < 8; ++j){
                    int r = (kc*32 + q*8 + j) * D_HID + m;
                    b0[j] = (short)f2bu(w[r]);      b1[j] = (short)f2bu(w[r + 16]);
                    b2[j] = (short)f2bu(w[r + 32]); b3[j] = (short)f2bu(w[r + 48]);
                }
            }
            ac0 = __builtin_amdgcn_mfma_f32_16x16x32_bf16(a, b0, ac0, 0, 0, 0);
            ac1 = __builtin_amdgcn_mfma_f32_16x16x32_bf16(a, b1, ac1, 0, 0, 0);
            ac2 = __builtin_amdgcn_mfma_f32_16x16x32_bf16(a, b2, ac2, 0, 0, 0);
            ac3 = __builtin_amdgcn_mfma_f32_16x16x32_bf16(a, b3, ac3, 0, 0, 0);
        }
        #pragma unroll
        for (int i = 0; i < 4; ++i){
            int nr = node0 + q*4 + i;
            if (nr < n){
                float di = s_dinv[nr - base];
                unsigned short* o = h1s + (size_t)nr * D_HID + m;
                o[0]  = (unsigned short)f2bu(ac0[i] * di);
                o[16] = (unsigned short)f2bu(ac1[i] * di);
                o[32] = (unsigned short)f2bu(ac2[i] * di);
                o[48] = (unsigned short)f2bu(ac3[i] * di);
            }
        }
    }
}

// ---------------- aggA + fused linear2 ----------------
__global__ __launch_bounds__(256) void k_aggA(
    const unsigned* __restrict__ off, const unsigned* __restrict__ offend,
    const int* __restrict__ csr_src,
    const float* __restrict__ dinv, const unsigned short* __restrict__ h1s,
    const unsigned* __restrict__ b1raw, const unsigned* __restrict__ w2raw,
    const int* __restrict__ flags,
    unsigned short* __restrict__ h2s, int n)
{
    __shared__ unsigned short act_s[16][72];   // 16-node act tile, padded

    const int lane = threadIdx.x & 63;
    const int wv   = threadIdx.x >> 6;
    const int grp  = lane >> 4;            // dst within wave (0..3)
    const int f    = lane & 15;            // uint2 index within 64-feature row
    const int dl   = wv * 4 + grp;         // dst within block (0..15)
    const int d    = blockIdx.x * 16 + dl;
    const int isBf16 = flags[0];

    bf16x8 w2f[2];
    if (wv == 0){
        const int m0 = lane & 15, q0 = lane >> 4;
        if (isBf16){
            const unsigned short* w = (const unsigned short*)w2raw;
            #pragma unroll
            for (int kc = 0; kc < 2; ++kc)
                #pragma unroll
                for (int j = 0; j < 8; ++j)
                    w2f[kc][j] = (short)w[(kc*32 + q0*8 + j) * D_OUT + m0];
        } else {
            const float* w = (const float*)w2raw;
            #pragma unroll
            for (int kc = 0; kc < 2; ++kc)
                #pragma unroll
                for (int j = 0; j < 8; ++j)
                    w2f[kc][j] = (short)f2bu(w[(kc*32 + q0*8 + j) * D_OUT + m0]);
        }
        if (blockIdx.x == 0 && lane < 4)
            ((uint2*)(h2s + (size_t)n * D_OUT))[lane] = make_uint2(0u, 0u);
    }

    if (d < n){
        const int beg = (int)off[d], end = (int)offend[d];
        float a0=0.f, a1=0.f, a2=0.f, a3=0.f;
        for (int i = beg; i < end; i += 8){
            uint4 cA = *(const uint4*)&csr_src[i];
            uint4 cB = *(const uint4*)&csr_src[i + 4];
            uint2 u0 = *(const uint2*)&h1s[(size_t)(unsigned)cA.x * D_HID + f * 4];
            uint2 u1 = *(const uint2*)&h1s[(size_t)(unsigned)cA.y * D_HID + f * 4];
            uint2 u2 = *(const uint2*)&h1s[(size_t)(unsigned)cA.z * D_HID + f * 4];
            uint2 u3 = *(const uint2*)&h1s[(size_t)(unsigned)cA.w * D_HID + f * 4];
            uint2 u4 = *(const uint2*)&h1s[(size_t)(unsigned)cB.x * D_HID + f * 4];
            uint2 u5 = *(const uint2*)&h1s[(size_t)(unsigned)cB.y * D_HID + f * 4];
            uint2 u6 = *(const uint2*)&h1s[(size_t)(unsigned)cB.z * D_HID + f * 4];
            uint2 u7 = *(const uint2*)&h1s[(size_t)(unsigned)cB.w * D_HID + f * 4];
            a0 += bflo(u0.x) + bflo(u1.x) + bflo(u2.x) + bflo(u3.x)
                + bflo(u4.x) + bflo(u5.x) + bflo(u6.x) + bflo(u7.x);
            a1 += bfhi(u0.x) + bfhi(u1.x) + bfhi(u2.x) + bfhi(u3.x)
                + bfhi(u4.x) + bfhi(u5.x) + bfhi(u6.x) + bfhi(u7.x);
            a2 += bflo(u0.y) + bflo(u1.y) + bflo(u2.y) + bflo(u3.y)
                + bflo(u4.y) + bflo(u5.y) + bflo(u6.y) + bflo(u7.y);
            a3 += bfhi(u0.y) + bfhi(u1.y) + bfhi(u2.y) + bfhi(u3.y)
                + bfhi(u4.y) + bfhi(u5.y) + bfhi(u6.y) + bfhi(u7.y);
        }
        uint2 su = *(const uint2*)&h1s[(size_t)d * D_HID + f * 4];
        a0 += bflo(su.x); a1 += bfhi(su.x);
        a2 += bflo(su.y); a3 += bfhi(su.y);
        const float dd = dinv[d];
        float b0, b1v, b2v, b3v;
        if (isBf16){
            uint2 bu = ((const uint2*)b1raw)[f];
            b0 = bflo(bu.x); b1v = bfhi(bu.x); b2v = bflo(bu.y); b3v = bfhi(bu.y);
        } else {
            float4 bb = ((const float4*)b1raw)[f];
            b0 = bb.x; b1v = bb.y; b2v = bb.z; b3v = bb.w;
        }
        act_s[dl][f*4+0] = (unsigned short)f2bu(sigf(fmaf(a0, dd, b0)));
        act_s[dl][f*4+1] = (unsigned short)f2bu(sigf(fmaf(a1, dd, b1v)));
        act_s[dl][f*4+2] = (unsigned short)f2bu(sigf(fmaf(a2, dd, b2v)));
        act_s[dl][f*4+3] = (unsigned short)f2bu(sigf(fmaf(a3, dd, b3v)));
    } else {
        #pragma unroll
        for (int j = 0; j < 4; ++j) act_s[dl][f*4+j] = 0;
    }
    __syncthreads();

    if (wv == 0){
        const int m0 = lane & 15, q0 = lane >> 4;
        f32x4 acc = {0,0,0,0};
        #pragma unroll
        for (int kc = 0; kc < 2; ++kc){
            bf16x8 a;
            #pragma unroll
            for (int j = 0; j < 8; ++j)
                a[j] = (short)act_s[m0][kc*32 + q0*8 + j];
            acc = __builtin_amdgcn_mfma_f32_16x16x32_bf16(a, w2f[kc], acc, 0, 0, 0);
        }
        #pragma unroll
        for (int i = 0; i < 4; ++i){
            int nr = blockIdx.x * 16 + q0*4 + i;
            if (nr < n)
                h2s[(size_t)nr * D_OUT + m0] = (unsigned short)f2bu(acc[i] * dinv[nr]);
        }
    }
}

// ---------------- aggB: 16 dst/wave, 4 lanes/dst, tail-free unroll x8 ----------------
__global__ __launch_bounds__(256) void k_aggB(
    const unsigned* __restrict__ off, const unsigned* __restrict__ offend,
    const int* __restrict__ csr_src,
    const float* __restrict__ dinv, const unsigned short* __restrict__ h2s,
    const unsigned* __restrict__ b2raw, const int* __restrict__ flags,
    void* __restrict__ out, int n)
{
    const int lane = threadIdx.x & 63;
    const int wv   = threadIdx.x >> 6;
    const int grp  = lane >> 2;            // dst within wave (0..15)
    const int f    = lane & 3;             // uint2 index within 16-feature row
    const int d    = (blockIdx.x * 4 + wv) * 16 + grp;
    const int isBf16 = flags[0];
    if (d >= n) return;

    const int beg = (int)off[d], end = (int)offend[d];
    float a0=0.f, a1=0.f, a2=0.f, a3=0.f;
    for (int i = beg; i < end; i += 8){
        uint4 cA = *(const uint4*)&csr_src[i];
        uint4 cB = *(const uint4*)&csr_src[i + 4];
        uint2 u0 = *(const uint2*)&h2s[(size_t)(unsigned)cA.x * D_OUT + f * 4];
        uint2 u1 = *(const uint2*)&h2s[(size_t)(unsigned)cA.y * D_OUT + f * 4];
        uint2 u2 = *(const uint2*)&h2s[(size_t)(unsigned)cA.z * D_OUT + f * 4];
        uint2 u3 = *(const uint2*)&h2s[(size_t)(unsigned)cA.w * D_OUT + f * 4];
        uint2 u4 = *(const uint2*)&h2s[(size_t)(unsigned)cB.x * D_OUT + f * 4];
        uint2 u5 = *(const uint2*)&h2s[(size_t)(unsigned)cB.y * D_OUT + f * 4];
        uint2 u6 = *(const uint2*)&h2s[(size_t)(unsigned)cB.z * D_OUT + f * 4];
        uint2 u7 = *(const uint2*)&h2s[(size_t)(unsigned)cB.w * D_OUT + f * 4];
        a0 += bflo(u0.x) + bflo(u1.x) + bflo(u2.x) + bflo(u3.x)
            + bflo(u4.x) + bflo(u5.x) + bflo(u6.x) + bflo(u7.x);
        a1 += bfhi(u0.x) + bfhi(u1.x) + bfhi(u2.x) + bfhi(u3.x)
            + bfhi(u4.x) + bfhi(u5.x) + bfhi(u6.x) + bfhi(u7.x);
        a2 += bflo(u0.y) + bflo(u1.y) + bflo(u2.y) + bflo(u3.y)
            + bflo(u4.y) + bflo(u5.y) + bflo(u6.y) + bflo(u7.y);
        a3 += bfhi(u0.y) + bfhi(u1.y) + bfhi(u2.y) + bfhi(u3.y)
            + bfhi(u4.y) + bfhi(u5.y) + bfhi(u6.y) + bfhi(u7.y);
    }
    uint2 su = *(const uint2*)&h2s[(size_t)d * D_OUT + f * 4];
    a0 += bflo(su.x); a1 += bfhi(su.x);
    a2 += bflo(su.y); a3 += bfhi(su.y);
    const float dd = dinv[d];
    float b0, b1v, b2v, b3v;
    if (isBf16){
        uint2 bu = ((const uint2*)b2raw)[f];
        b0 = bflo(bu.x); b1v = bfhi(bu.x); b2v = bflo(bu.y); b3v = bfhi(bu.y);
    } else {
        float4 bb = ((const float4*)b2raw)[f];
        b0 = bb.x; b1v = bb.y; b2v = bb.z; b3v = bb.w;
    }
    a0 = fmaf(a0, dd, b0); a1 = fmaf(a1, dd, b1v);
    a2 = fmaf(a2, dd, b2v); a3 = fmaf(a3, dd, b3v);
    float m = fmaxf(fmaxf(a0, a1), fmaxf(a2, a3));
    m = fmaxf(m, __shfl_xor(m, 1, 4));
    m = fmaxf(m, __shfl_xor(m, 2, 4));
    float s = __expf(a0 - m) + __expf(a1 - m) + __expf(a2 - m) + __expf(a3 - m);
    s += __shfl_xor(s, 1, 4);
    s += __shfl_xor(s, 2, 4);
    float ls = m + __logf(s);
    if (isBf16){
        uint2 pk;
        pk.x = f2bu(a0 - ls) | (f2bu(a1 - ls) << 16);
        pk.y = f2bu(a2 - ls) | (f2bu(a3 - ls) << 16);
        *(uint2*)((__hip_bfloat16*)out + (size_t)d * D_OUT + f * 4) = pk;
    } else {
        float4 o4 = make_float4(a0 - ls, a1 - ls, a2 - ls, a3 - ls);
        *(float4*)((float*)out + (size_t)d * D_OUT + f * 4) = o4;
    }
}

extern "C" void kernel_launch(void* const* d_in, const int* in_sizes, int n_in,
                              void* d_out, int out_size, void* d_ws, size_t ws_size,
                              hipStream_t stream)
{
    const unsigned* xraw  = (const unsigned*)d_in[0];
    const int*      ei    = (const int*)d_in[1];
    const unsigned* w1raw = (const unsigned*)d_in[2];
    const unsigned* b1raw = (const unsigned*)d_in[3];
    const unsigned* w2raw = (const unsigned*)d_in[4];
    const unsigned* b2raw = (const unsigned*)d_in[5];

    const int n  = in_sizes[0] / D_IN;   // 100000
    const int ne = in_sizes[1] / 2;      // 1600000
    const int B  = (n + ((1 << WSHIFT) - 1)) >> WSHIFT;   // 196 buckets

    // ws layout (4B words):
    // flags[64] | gcur[256] | dinv[nAl] | off[nAl] | offend[nAl] | csr[MAXB*CSRCAP]
    //   | gbuf[MAXB*BCAP] | h1s[(n+16)*64 bf16] | h2s[(n+16)*16 bf16]
    size_t nAl = ((size_t)n + 255) & ~(size_t)255;
    int*            flags  = (int*)d_ws;
    unsigned*       gcur   = (unsigned*)d_ws + 64;
    float*          dinv   = (float*)(gcur + 256);
    unsigned*       off    = (unsigned*)(dinv + nAl);
    unsigned*       offend = off + nAl;
    int*            csr    = (int*)(offend + nAl);
    unsigned*       gbuf   = (unsigned*)(csr + (size_t)MAXB * CSRCAP);
    unsigned short* h1s    = (unsigned short*)(gbuf + (size_t)MAXB * BCAP);
    unsigned short* h2s    = h1s + (size_t)(n + 16) * D_HID;

    const int nchunk = (ne + CHUNK - 1) / CHUNK;   // 782 @ CHUNK=2048

    hipMemsetAsync(gcur, 0, MAXB * sizeof(unsigned), stream);
    k_bucketize  <<<nchunk, 256, 0, stream>>>(ei, xraw, flags, gcur, gbuf, ne, B);
    k_build_lin1 <<<B, 1024, 0, stream>>>(gbuf, gcur, off, offend, dinv, csr,
                                          xraw, w1raw, flags, h1s, n, B);
    k_aggA       <<<(n + 15) / 16, 256, 0, stream>>>(off, offend, csr, dinv, h1s, b1raw, w2raw, flags, h2s, n);
    k_aggB       <<<(n + 63) / 64, 256, 0, stream>>>(off, offend, csr, dinv, h2s, b2raw, flags, d_out, n);
}

// Round 4
// 206.300 us; speedup vs baseline: 3.7547x; 1.8286x over previous
//
#include <hip/hip_runtime.h>
#include <hip/hip_bf16.h>

// GCN 2-layer. Bucketized padded-CSR build, pre-scaled bf16 intermediates
// (h1s = h1*dinv => per-edge work = gather+add), MFMA linear1 (grid-saturated:
// 1 tile/wave), linear2 FUSED into aggA (LDS act tile + wave-0 MFMA -> h2s).
// SEPARATE kernels per phase — measured (R2/R3): any fusion that mixes a
// streaming read or a grid-wide barrier into a scatter/gather phase destroys
// per-XCD L2 residency and costs 2-3x. R0 structure, bucketize at CHUNK=2048
// (782 blocks ~ 3 blocks/CU co-resident; was 391 @ 1.5/CU, CU-starved).
// flags[0]=1 if floats bf16 else fp32; flags[1]=1 if edge_index int64 else int32.

constexpr int D_IN  = 128;
constexpr int D_HID = 64;
constexpr int D_OUT = 16;

constexpr int WSHIFT  = 9;       // bucket = dst >> 9 (512 nodes/bucket)
constexpr int MAXB    = 256;     // max buckets (n <= 131072)
constexpr int BCAP    = 12288;   // gbuf bucket capacity (mean ~8163 at E/N=16)
constexpr int CSRCAP  = 16384;   // csr bucket region (BCAP + 512*8 padding)
constexpr int BIN_CAP = 48;      // LDS bin cap per bucket per chunk (mean ~10.5 @ CHUNK=2048)
constexpr int CHUNK   = 2048;    // 782 blocks -> ~3 blocks/CU co-resident

typedef __attribute__((ext_vector_type(8))) short bf16x8;
typedef __attribute__((ext_vector_type(4))) float f32x4;

__device__ inline float bflo(unsigned u){ return __uint_as_float(u << 16); }
__device__ inline float bfhi(unsigned u){ return __uint_as_float(u & 0xffff0000u); }
__device__ inline unsigned f2bu(float f){
    __hip_bfloat16 h = __float2bfloat16(f);
    return (unsigned)*reinterpret_cast<unsigned short*>(&h);
}
__device__ inline float sigf(float x){ return 1.0f / (1.0f + __expf(-x)); }

// ---------------- phase 1: bucketize edges by dst>>9 + on-device dtype detect ----------------
__global__ __launch_bounds__(256) void k_bucketize(
    const int* __restrict__ ei, const unsigned* __restrict__ xraw,
    int* __restrict__ flags, unsigned* __restrict__ gcur,
    unsigned* __restrict__ gbuf, int ne, int B)
{
    __shared__ unsigned bcnt[MAXB];
    __shared__ unsigned bbase[MAXB];
    __shared__ unsigned bins[MAXB * BIN_CAP];   // 48 KB; total ~50 KB -> 3 blocks/CU
    __shared__ int s_i64;

    const int t = threadIdx.x, lane = t & 63, wv = t >> 6;
    const int e0 = blockIdx.x * CHUNK;

    if (t < MAXB) bcnt[t] = 0u;
    if (wv == 0){
        int w = ei[2 * lane + 1];
        unsigned long long m = __ballot(w == 0);
        if (lane == 0) s_i64 = (__popcll(m) > 48) ? 1 : 0;
        if (blockIdx.x == 0){
            unsigned u = xraw[lane];
            unsigned h0 = u & 0xffffu, h1 = u >> 16;
            unsigned ex0 = (h0 >> 7) & 0xffu, ex1 = (h1 >> 7) & 0xffu;
            bool bad0 = !((h0 & 0x7fffu) == 0 || (ex0 >= 97 && ex0 <= 157));
            bool bad1 = !((h1 & 0x7fffu) == 0 || (ex1 >= 97 && ex1 <= 157));
            unsigned long long m0 = __ballot(bad0);
            unsigned long long m1 = __ballot(bad1);
            if (lane == 0){
                int bad = __popcll(m0) + __popcll(m1);
                flags[0] = (bad > 8) ? 0 : 1;
                flags[1] = s_i64;
            }
        }
    }
    __syncthreads();
    const int i64 = s_i64;
    const bool vec = ((ne & 1) == 0);

    #pragma unroll
    for (int k = 0; k < CHUNK / 512; ++k){
        int e = e0 + k * 512 + 2 * t;
        int s0, d0, s1, d1;
        int cntE = 0;
        if (vec && e < ne){
            if (i64){
                int4 sp = *(const int4*)&ei[2 * e];
                int4 dp = *(const int4*)&ei[2 * (ne + e)];
                s0 = sp.x; s1 = sp.z; d0 = dp.x; d1 = dp.z;
            } else {
                int2 sp = *(const int2*)&ei[e];
                int2 dp = *(const int2*)&ei[ne + e];
                s0 = sp.x; s1 = sp.y; d0 = dp.x; d1 = dp.y;
            }
            cntE = 2;
        } else {
            if (e < ne){
                if (i64){ s0 = ei[2*e]; d0 = ei[2*(ne+e)]; }
                else    { s0 = ei[e];   d0 = ei[ne+e]; }
                cntE = 1;
                if (e + 1 < ne){
                    if (i64){ s1 = ei[2*(e+1)]; d1 = ei[2*(ne+e+1)]; }
                    else    { s1 = ei[e+1];     d1 = ei[ne+e+1]; }
                    cntE = 2;
                }
            }
        }
        #pragma unroll
        for (int j = 0; j < 2; ++j){
            if (j < cntE){
                int s = j ? s1 : s0, d = j ? d1 : d0;
                int b = d >> WSHIFT;
                unsigned v = ((unsigned)s << WSHIFT) | ((unsigned)d & ((1u << WSHIFT) - 1));
                unsigned p = atomicAdd(&bcnt[b], 1u);
                if (p < (unsigned)BIN_CAP){
                    bins[b * BIN_CAP + p] = v;
                } else {
                    unsigned g = atomicAdd(&gcur[b], 1u);
                    gbuf[(size_t)b * BCAP + g] = v;
                }
            }
        }
    }
    __syncthreads();

    if (t < B){
        unsigned c = min(bcnt[t], (unsigned)BIN_CAP);
        bbase[t] = atomicAdd(&gcur[t], c);
    }
    __syncthreads();

    for (int b = wv; b < B; b += 4){
        unsigned c = min(bcnt[b], (unsigned)BIN_CAP);
        unsigned ba = bbase[b];
        for (unsigned o = lane; o < c; o += 64)
            gbuf[(size_t)b * BCAP + ba + o] = bins[b * BIN_CAP + o];
    }
}

// ---------------- phase 2: per-bucket hist + scan + PADDED csr fill ----------------
__global__ __launch_bounds__(1024) void k_build(
    const unsigned* __restrict__ gbuf, const unsigned* __restrict__ gcnt,
    unsigned* __restrict__ off, unsigned* __restrict__ offend,
    float* __restrict__ dinv, int* __restrict__ csr, int n, int B)
{
    __shared__ unsigned hist[512];
    __shared__ unsigned offl[512];
    __shared__ unsigned wsums[8];

    const int t = threadIdx.x, lane = t & 63, wv = t >> 6;
    const int b = blockIdx.x;
    const int base = b << WSHIFT;
    const int nodes = min(512, n - base);
    const unsigned bb = (unsigned)b * CSRCAP;

    if (t < 512) hist[t] = 0u;
    __syncthreads();
    const unsigned cnt = gcnt[b];
    const unsigned* mybuf = gbuf + (size_t)b * BCAP;

    for (unsigned i = t; i < cnt; i += 1024)
        atomicAdd(&hist[mybuf[i] & ((1u << WSHIFT) - 1)], 1u);
    __syncthreads();

    unsigned v = 0, p = 0, x = 0;
    if (t < 512){
        v = hist[t];
        p = (v + 7u) & ~7u;
        x = p;
        #pragma unroll
        for (int o = 1; o < 64; o <<= 1){
            unsigned y = __shfl_up(x, o, 64);
            if (lane >= o) x += y;
        }
        if (lane == 63) wsums[wv] = x;
    }
    __syncthreads();
    if (t == 0){
        unsigned run = 0;
        #pragma unroll
        for (int w = 0; w < 8; ++w){ unsigned tv = wsums[w]; wsums[w] = run; run += tv; }
    }
    __syncthreads();
    if (t < 512) offl[t] = x - p + wsums[wv];
    __syncthreads();

    if (t < nodes){
        off[base + t]    = bb + offl[t];
        offend[base + t] = bb + offl[t] + p;
        dinv[base + t]   = rsqrtf(1.0f + (float)v);
    }
    __syncthreads();

    if (t < 512) hist[t] = offl[t];
    __syncthreads();

    for (unsigned i = t; i < cnt; i += 1024){
        unsigned rec = mybuf[i];
        unsigned pos = atomicAdd(&hist[rec & ((1u << WSHIFT) - 1)], 1u);
        csr[bb + pos] = (int)(rec >> WSHIFT);
    }
    __syncthreads();

    if (t < nodes){
        unsigned s = offl[t] + v, e2 = offl[t] + p;
        for (unsigned j = s; j < e2; ++j) csr[bb + j] = n;
    }
}

// ---------------- linear 1 (MFMA): h1s(bf16) = (x @ W1) * dinv[node]; row n = 0 ----------------
// Grid-saturated: one 16-node tile per wave.
__global__ __launch_bounds__(256) void k_linear1(
    const unsigned* __restrict__ xraw, const unsigned* __restrict__ w1raw,
    const int* __restrict__ flags, const float* __restrict__ dinv,
    unsigned short* __restrict__ h1s, int n)
{
    const int lane = threadIdx.x & 63;
    const int wv   = threadIdx.x >> 6;
    const int m = lane & 15, q = lane >> 4;
    const int isBf16 = flags[0];

    if (blockIdx.x == 0 && threadIdx.x < 16)
        ((uint2*)(h1s + (size_t)n * D_HID))[threadIdx.x] = make_uint2(0u, 0u);

    bf16x8 bfr[4][4];
    if (isBf16){
        const unsigned short* w = (const unsigned short*)w1raw;
        #pragma unroll
        for (int kc = 0; kc < 4; ++kc)
            #pragma unroll
            for (int ct = 0; ct < 4; ++ct)
                #pragma unroll
                for (int j = 0; j < 8; ++j)
                    bfr[kc][ct][j] = (short)w[(kc*32 + q*8 + j) * D_HID + ct*16 + m];
    } else {
        const float* w = (const float*)w1raw;
        #pragma unroll
        for (int kc = 0; kc < 4; ++kc)
            #pragma unroll
            for (int ct = 0; ct < 4; ++ct)
                #pragma unroll
                for (int j = 0; j < 8; ++j)
                    bfr[kc][ct][j] = (short)f2bu(w[(kc*32 + q*8 + j) * D_HID + ct*16 + m]);
    }

    const int ntiles = (n + 15) >> 4;
    for (int tile = blockIdx.x * 4 + wv; tile < ntiles; tile += gridDim.x * 4){
        const int node0 = tile << 4;
        int arow = node0 + m; if (arow >= n) arow = n - 1;
        f32x4 ac0 = {0,0,0,0}, ac1 = {0,0,0,0}, ac2 = {0,0,0,0}, ac3 = {0,0,0,0};
        #pragma unroll
        for (int kc = 0; kc < 4; ++kc){
            bf16x8 a;
            if (isBf16){
                uint4 u = *(const uint4*)((const unsigned short*)xraw + (size_t)arow * D_IN + kc*32 + q*8);
                a = *reinterpret_cast<bf16x8*>(&u);
            } else {
                const float* xp = (const float*)xraw + (size_t)arow * D_IN + kc*32 + q*8;
                float4 f0 = *(const float4*)xp;
                float4 f1 = *(const float4*)(xp + 4);
                a[0]=(short)f2bu(f0.x); a[1]=(short)f2bu(f0.y); a[2]=(short)f2bu(f0.z); a[3]=(short)f2bu(f0.w);
                a[4]=(short)f2bu(f1.x); a[5]=(short)f2bu(f1.y); a[6]=(short)f2bu(f1.z); a[7]=(short)f2bu(f1.w);
            }
            ac0 = __builtin_amdgcn_mfma_f32_16x16x32_bf16(a, bfr[kc][0], ac0, 0, 0, 0);
            ac1 = __builtin_amdgcn_mfma_f32_16x16x32_bf16(a, bfr[kc][1], ac1, 0, 0, 0);
            ac2 = __builtin_amdgcn_mfma_f32_16x16x32_bf16(a, bfr[kc][2], ac2, 0, 0, 0);
            ac3 = __builtin_amdgcn_mfma_f32_16x16x32_bf16(a, bfr[kc][3], ac3, 0, 0, 0);
        }
        #pragma unroll
        for (int i = 0; i < 4; ++i){
            int nr = node0 + q*4 + i;
            if (nr < n){
                float di = dinv[nr];
                unsigned short* o = h1s + (size_t)nr * D_HID + m;
                o[0]  = (unsigned short)f2bu(ac0[i] * di);
                o[16] = (unsigned short)f2bu(ac1[i] * di);
                o[32] = (unsigned short)f2bu(ac2[i] * di);
                o[48] = (unsigned short)f2bu(ac3[i] * di);
            }
        }
    }
}

// ---------------- aggA + fused linear2 ----------------
__global__ __launch_bounds__(256) void k_aggA(
    const unsigned* __restrict__ off, const unsigned* __restrict__ offend,
    const int* __restrict__ csr_src,
    const float* __restrict__ dinv, const unsigned short* __restrict__ h1s,
    const unsigned* __restrict__ b1raw, const unsigned* __restrict__ w2raw,
    const int* __restrict__ flags,
    unsigned short* __restrict__ h2s, int n)
{
    __shared__ unsigned short act_s[16][72];   // 16-node act tile, padded

    const int lane = threadIdx.x & 63;
    const int wv   = threadIdx.x >> 6;
    const int grp  = lane >> 4;            // dst within wave (0..3)
    const int f    = lane & 15;            // uint2 index within 64-feature row
    const int dl   = wv * 4 + grp;         // dst within block (0..15)
    const int d    = blockIdx.x * 16 + dl;
    const int isBf16 = flags[0];

    bf16x8 w2f[2];
    if (wv == 0){
        const int m0 = lane & 15, q0 = lane >> 4;
        if (isBf16){
            const unsigned short* w = (const unsigned short*)w2raw;
            #pragma unroll
            for (int kc = 0; kc < 2; ++kc)
                #pragma unroll
                for (int j = 0; j < 8; ++j)
                    w2f[kc][j] = (short)w[(kc*32 + q0*8 + j) * D_OUT + m0];
        } else {
            const float* w = (const float*)w2raw;
            #pragma unroll
            for (int kc = 0; kc < 2; ++kc)
                #pragma unroll
                for (int j = 0; j < 8; ++j)
                    w2f[kc][j] = (short)f2bu(w[(kc*32 + q0*8 + j) * D_OUT + m0]);
        }
        if (blockIdx.x == 0 && lane < 4)
            ((uint2*)(h2s + (size_t)n * D_OUT))[lane] = make_uint2(0u, 0u);
    }

    if (d < n){
        const int beg = (int)off[d], end = (int)offend[d];
        float a0=0.f, a1=0.f, a2=0.f, a3=0.f;
        for (int i = beg; i < end; i += 8){
            uint4 cA = *(const uint4*)&csr_src[i];
            uint4 cB = *(const uint4*)&csr_src[i + 4];
            uint2 u0 = *(const uint2*)&h1s[(size_t)(unsigned)cA.x * D_HID + f * 4];
            uint2 u1 = *(const uint2*)&h1s[(size_t)(unsigned)cA.y * D_HID + f * 4];
            uint2 u2 = *(const uint2*)&h1s[(size_t)(unsigned)cA.z * D_HID + f * 4];
            uint2 u3 = *(const uint2*)&h1s[(size_t)(unsigned)cA.w * D_HID + f * 4];
            uint2 u4 = *(const uint2*)&h1s[(size_t)(unsigned)cB.x * D_HID + f * 4];
            uint2 u5 = *(const uint2*)&h1s[(size_t)(unsigned)cB.y * D_HID + f * 4];
            uint2 u6 = *(const uint2*)&h1s[(size_t)(unsigned)cB.z * D_HID + f * 4];
            uint2 u7 = *(const uint2*)&h1s[(size_t)(unsigned)cB.w * D_HID + f * 4];
            a0 += bflo(u0.x) + bflo(u1.x) + bflo(u2.x) + bflo(u3.x)
                + bflo(u4.x) + bflo(u5.x) + bflo(u6.x) + bflo(u7.x);
            a1 += bfhi(u0.x) + bfhi(u1.x) + bfhi(u2.x) + bfhi(u3.x)
                + bfhi(u4.x) + bfhi(u5.x) + bfhi(u6.x) + bfhi(u7.x);
            a2 += bflo(u0.y) + bflo(u1.y) + bflo(u2.y) + bflo(u3.y)
                + bflo(u4.y) + bflo(u5.y) + bflo(u6.y) + bflo(u7.y);
            a3 += bfhi(u0.y) + bfhi(u1.y) + bfhi(u2.y) + bfhi(u3.y)
                + bfhi(u4.y) + bfhi(u5.y) + bfhi(u6.y) + bfhi(u7.y);
        }
        uint2 su = *(const uint2*)&h1s[(size_t)d * D_HID + f * 4];
        a0 += bflo(su.x); a1 += bfhi(su.x);
        a2 += bflo(su.y); a3 += bfhi(su.y);
        const float dd = dinv[d];
        float b0, b1v, b2v, b3v;
        if (isBf16){
            uint2 bu = ((const uint2*)b1raw)[f];
            b0 = bflo(bu.x); b1v = bfhi(bu.x); b2v = bflo(bu.y); b3v = bfhi(bu.y);
        } else {
            float4 bb = ((const float4*)b1raw)[f];
            b0 = bb.x; b1v = bb.y; b2v = bb.z; b3v = bb.w;
        }
        act_s[dl][f*4+0] = (unsigned short)f2bu(sigf(fmaf(a0, dd, b0)));
        act_s[dl][f*4+1] = (unsigned short)f2bu(sigf(fmaf(a1, dd, b1v)));
        act_s[dl][f*4+2] = (unsigned short)f2bu(sigf(fmaf(a2, dd, b2v)));
        act_s[dl][f*4+3] = (unsigned short)f2bu(sigf(fmaf(a3, dd, b3v)));
    } else {
        #pragma unroll
        for (int j = 0; j < 4; ++j) act_s[dl][f*4+j] = 0;
    }
    __syncthreads();

    if (wv == 0){
        const int m0 = lane & 15, q0 = lane >> 4;
        f32x4 acc = {0,0,0,0};
        #pragma unroll
        for (int kc = 0; kc < 2; ++kc){
            bf16x8 a;
            #pragma unroll
            for (int j = 0; j < 8; ++j)
                a[j] = (short)act_s[m0][kc*32 + q0*8 + j];
            acc = __builtin_amdgcn_mfma_f32_16x16x32_bf16(a, w2f[kc], acc, 0, 0, 0);
        }
        #pragma unroll
        for (int i = 0; i < 4; ++i){
            int nr = blockIdx.x * 16 + q0*4 + i;
            if (nr < n)
                h2s[(size_t)nr * D_OUT + m0] = (unsigned short)f2bu(acc[i] * dinv[nr]);
        }
    }
}

// ---------------- aggB: 16 dst/wave, 4 lanes/dst, tail-free unroll x8 ----------------
__global__ __launch_bounds__(256) void k_aggB(
    const unsigned* __restrict__ off, const unsigned* __restrict__ offend,
    const int* __restrict__ csr_src,
    const float* __restrict__ dinv, const unsigned short* __restrict__ h2s,
    const unsigned* __restrict__ b2raw, const int* __restrict__ flags,
    void* __restrict__ out, int n)
{
    const int lane = threadIdx.x & 63;
    const int wv   = threadIdx.x >> 6;
    const int grp  = lane >> 2;            // dst within wave (0..15)
    const int f    = lane & 3;             // uint2 index within 16-feature row
    const int d    = (blockIdx.x * 4 + wv) * 16 + grp;
    const int isBf16 = flags[0];
    if (d >= n) return;

    const int beg = (int)off[d], end = (int)offend[d];
    float a0=0.f, a1=0.f, a2=0.f, a3=0.f;
    for (int i = beg; i < end; i += 8){
        uint4 cA = *(const uint4*)&csr_src[i];
        uint4 cB = *(const uint4*)&csr_src[i + 4];
        uint2 u0 = *(const uint2*)&h2s[(size_t)(unsigned)cA.x * D_OUT + f * 4];
        uint2 u1 = *(const uint2*)&h2s[(size_t)(unsigned)cA.y * D_OUT + f * 4];
        uint2 u2 = *(const uint2*)&h2s[(size_t)(unsigned)cA.z * D_OUT + f * 4];
        uint2 u3 = *(const uint2*)&h2s[(size_t)(unsigned)cA.w * D_OUT + f * 4];
        uint2 u4 = *(const uint2*)&h2s[(size_t)(unsigned)cB.x * D_OUT + f * 4];
        uint2 u5 = *(const uint2*)&h2s[(size_t)(unsigned)cB.y * D_OUT + f * 4];
        uint2 u6 = *(const uint2*)&h2s[(size_t)(unsigned)cB.z * D_OUT + f * 4];
        uint2 u7 = *(const uint2*)&h2s[(size_t)(unsigned)cB.w * D_OUT + f * 4];
        a0 += bflo(u0.x) + bflo(u1.x) + bflo(u2.x) + bflo(u3.x)
            + bflo(u4.x) + bflo(u5.x) + bflo(u6.x) + bflo(u7.x);
        a1 += bfhi(u0.x) + bfhi(u1.x) + bfhi(u2.x) + bfhi(u3.x)
            + bfhi(u4.x) + bfhi(u5.x) + bfhi(u6.x) + bfhi(u7.x);
        a2 += bflo(u0.y) + bflo(u1.y) + bflo(u2.y) + bflo(u3.y)
            + bflo(u4.y) + bflo(u5.y) + bflo(u6.y) + bflo(u7.y);
        a3 += bfhi(u0.y) + bfhi(u1.y) + bfhi(u2.y) + bfhi(u3.y)
            + bfhi(u4.y) + bfhi(u5.y) + bfhi(u6.y) + bfhi(u7.y);
    }
    uint2 su = *(const uint2*)&h2s[(size_t)d * D_OUT + f * 4];
    a0 += bflo(su.x); a1 += bfhi(su.x);
    a2 += bflo(su.y); a3 += bfhi(su.y);
    const float dd = dinv[d];
    float b0, b1v, b2v, b3v;
    if (isBf16){
        uint2 bu = ((const uint2*)b2raw)[f];
        b0 = bflo(bu.x); b1v = bfhi(bu.x); b2v = bflo(bu.y); b3v = bfhi(bu.y);
    } else {
        float4 bb = ((const float4*)b2raw)[f];
        b0 = bb.x; b1v = bb.y; b2v = bb.z; b3v = bb.w;
    }
    a0 = fmaf(a0, dd, b0); a1 = fmaf(a1, dd, b1v);
    a2 = fmaf(a2, dd, b2v); a3 = fmaf(a3, dd, b3v);
    float m = fmaxf(fmaxf(a0, a1), fmaxf(a2, a3));
    m = fmaxf(m, __shfl_xor(m, 1, 4));
    m = fmaxf(m, __shfl_xor(m, 2, 4));
    float s = __expf(a0 - m) + __expf(a1 - m) + __expf(a2 - m) + __expf(a3 - m);
    s += __shfl_xor(s, 1, 4);
    s += __shfl_xor(s, 2, 4);
    float ls = m + __logf(s);
    if (isBf16){
        uint2 pk;
        pk.x = f2bu(a0 - ls) | (f2bu(a1 - ls) << 16);
        pk.y = f2bu(a2 - ls) | (f2bu(a3 - ls) << 16);
        *(uint2*)((__hip_bfloat16*)out + (size_t)d * D_OUT + f * 4) = pk;
    } else {
        float4 o4 = make_float4(a0 - ls, a1 - ls, a2 - ls, a3 - ls);
        *(float4*)((float*)out + (size_t)d * D_OUT + f * 4) = o4;
    }
}

extern "C" void kernel_launch(void* const* d_in, const int* in_sizes, int n_in,
                              void* d_out, int out_size, void* d_ws, size_t ws_size,
                              hipStream_t stream)
{
    const unsigned* xraw  = (const unsigned*)d_in[0];
    const int*      ei    = (const int*)d_in[1];
    const unsigned* w1raw = (const unsigned*)d_in[2];
    const unsigned* b1raw = (const unsigned*)d_in[3];
    const unsigned* w2raw = (const unsigned*)d_in[4];
    const unsigned* b2raw = (const unsigned*)d_in[5];

    const int n  = in_sizes[0] / D_IN;   // 100000
    const int ne = in_sizes[1] / 2;      // 1600000
    const int B  = (n + ((1 << WSHIFT) - 1)) >> WSHIFT;   // 196 buckets

    // ws layout (4B words):
    // flags[64] | gcur[256] | dinv[nAl] | off[nAl] | offend[nAl] | csr[MAXB*CSRCAP]
    //   | gbuf[MAXB*BCAP] | h1s[(n+16)*64 bf16] | h2s[(n+16)*16 bf16]
    size_t nAl = ((size_t)n + 255) & ~(size_t)255;
    int*            flags  = (int*)d_ws;
    unsigned*       gcur   = (unsigned*)d_ws + 64;
    float*          dinv   = (float*)(gcur + 256);
    unsigned*       off    = (unsigned*)(dinv + nAl);
    unsigned*       offend = off + nAl;
    int*            csr    = (int*)(offend + nAl);
    unsigned*       gbuf   = (unsigned*)(csr + (size_t)MAXB * CSRCAP);
    unsigned short* h1s    = (unsigned short*)(gbuf + (size_t)MAXB * BCAP);
    unsigned short* h2s    = h1s + (size_t)(n + 16) * D_HID;

    const int nchunk  = (ne + CHUNK - 1) / CHUNK;   // 782 @ CHUNK=2048
    const int ntiles1 = (n + 15) / 16;
    const int grid1   = (ntiles1 + 3) / 4;    // one 16-node tile per wave

    hipMemsetAsync(gcur, 0, MAXB * sizeof(unsigned), stream);
    k_bucketize <<<nchunk, 256, 0, stream>>>(ei, xraw, flags, gcur, gbuf, ne, B);
    k_build     <<<B, 1024, 0, stream>>>(gbuf, gcur, off, offend, dinv, csr, n, B);

    k_linear1   <<<grid1, 256, 0, stream>>>(xraw, w1raw, flags, dinv, h1s, n);
    k_aggA      <<<(n + 15) / 16, 256, 0, stream>>>(off, offend, csr, dinv, h1s, b1raw, w2raw, flags, h2s, n);
    k_aggB      <<<(n + 63) / 64, 256, 0, stream>>>(off, offend, csr, dinv, h2s, b2raw, flags, d_out, n);
}